// Round 1
// baseline (4186.570 us; speedup 1.0000x reference)
//
#include <hip/hip_runtime.h>

#define N0 262144
#define N1 65536
#define N2 16384
#define NNET 200000
#define E0 2097152
#define E1 524288
#define E2 131072
#define ECONN 800000

// ---------- helpers ----------
__device__ __forceinline__ unsigned ordf(float f) {
    unsigned u = __float_as_uint(f);
    return (u & 0x80000000u) ? ~u : (u | 0x80000000u);
}
__device__ __forceinline__ float unordf(unsigned o) {
    return __uint_as_float((o & 0x80000000u) ? (o & 0x7fffffffu) : ~o);
}

// ---------- degree / count ----------
__global__ void deg_kernel(const int* __restrict__ idx, int n, float* __restrict__ deg) {
    int t = blockIdx.x * blockDim.x + threadIdx.x;
    if (t < n) atomicAdd(&deg[idx[t]], 1.0f);
}

// ---------- edge scatter-add (segment sum). src==nullptr -> identity (pooling) ----------
template<int F>
__global__ void scatter_add(const float* __restrict__ x, const int* __restrict__ src,
                            const int* __restrict__ dst, int nE, float* __restrict__ acc) {
    const int C = F / 4;
    int t = blockIdx.x * blockDim.x + threadIdx.x;
    int e = t / C, c = t % C;
    if (e >= nE) return;
    int s = src ? src[e] : e;
    int d = dst[e];
    const float4 v = *reinterpret_cast<const float4*>(&x[(size_t)s * F + c * 4]);
    float* a = &acc[(size_t)d * F + c * 4];
    atomicAdd(a + 0, v.x);
    atomicAdd(a + 1, v.y);
    atomicAdd(a + 2, v.z);
    atomicAdd(a + 3, v.w);
}

// ---------- divide accumulated sum by count (in place) ----------
template<int F>
__global__ void div_by_count(float* __restrict__ x, const float* __restrict__ cnt, int n) {
    int t = blockIdx.x * blockDim.x + threadIdx.x;
    if (t >= n * F) return;
    int node = t / F;
    x[t] = x[t] / fmaxf(cnt[node], 1.0f);
}

// ---------- SAGE node kernel: h = tanh(x@Ws + (agg/deg)@Wn + b) ----------
template<int DIN, int DOUT>
__global__ void sage_kernel(const float* __restrict__ x, const float* __restrict__ agg,
                            const float* __restrict__ deg,
                            const float* __restrict__ Ws, const float* __restrict__ Wn,
                            const float* __restrict__ b, float* __restrict__ h, int n) {
    __shared__ float ws[DIN * DOUT];
    __shared__ float wn[DIN * DOUT];
    __shared__ float bs[DOUT];
    for (int i = threadIdx.x; i < DIN * DOUT; i += blockDim.x) { ws[i] = Ws[i]; wn[i] = Wn[i]; }
    if (threadIdx.x < DOUT) bs[threadIdx.x] = b[threadIdx.x];
    __syncthreads();
    const int NPB = 256 / DOUT;
    int node = blockIdx.x * NPB + threadIdx.x / DOUT;
    int j = threadIdx.x % DOUT;
    if (node >= n) return;
    float scale = 1.0f / fmaxf(deg[node], 1.0f);
    const float* xr = &x[(size_t)node * DIN];
    const float* ar = &agg[(size_t)node * DIN];
    float acc = bs[j];
#pragma unroll
    for (int i = 0; i < DIN; ++i)
        acc += xr[i] * ws[i * DOUT + j] + (ar[i] * scale) * wn[i * DOUT + j];
    h[(size_t)node * DOUT + j] = tanhf(acc);
}

// ---------- cat[n] = [hup[assign[n]] (32) , hlo[n] (32)] ----------
__global__ void concat_kernel(const float* __restrict__ hup, const int* __restrict__ assign,
                              const float* __restrict__ hlo, float* __restrict__ cat, int n) {
    int t = blockIdx.x * blockDim.x + threadIdx.x;
    if (t >= n * 64) return;
    int node = t >> 6, f = t & 63;
    float v = (f < 32) ? hup[(size_t)assign[node] * 32 + f]
                       : hlo[(size_t)node * 32 + (f - 32)];
    cat[t] = v;
}

// ---------- init orderable-encoded -inf ----------
__global__ void init_ord(unsigned* __restrict__ p, int n) {
    int t = blockIdx.x * blockDim.x + threadIdx.x;
    if (t < n) p[t] = 0x007FFFFFu; // ordf(-inf)
}

// ---------- per-net segment max over conn edges ----------
__global__ void conn_max(const float* __restrict__ h0b, const int* __restrict__ csrc,
                         const int* __restrict__ cdst, unsigned* __restrict__ ymax,
                         unsigned* __restrict__ ymin) {
    int t = blockIdx.x * blockDim.x + threadIdx.x;
    if (t >= ECONN * 32) return;
    int e = t >> 5, f = t & 31;
    int s = csrc[e], d = cdst[e];
    float a  = h0b[(size_t)s * 64 + f];
    float bb = h0b[(size_t)s * 64 + 32 + f];
    atomicMax(&ymax[(size_t)d * 32 + f], ordf(a));
    atomicMax(&ymin[(size_t)d * 32 + f], ordf(bb));
}

// ---------- fused MLP: one wave per net ----------
__global__ void mlp_kernel(const unsigned* __restrict__ ymax, const unsigned* __restrict__ ymin,
                           const float* __restrict__ xnet,
                           const float* __restrict__ w1, const float* __restrict__ b1,
                           const float* __restrict__ w2, const float* __restrict__ b2,
                           float* __restrict__ out) {
    __shared__ float w1s[80 * 64];
    __shared__ float w2s[64];
    __shared__ float xin[4][80];
    for (int i = threadIdx.x; i < 80 * 64; i += blockDim.x) w1s[i] = w1[i];
    if (threadIdx.x < 64) w2s[threadIdx.x] = w2[threadIdx.x];
    int wv = threadIdx.x >> 6;
    int lane = threadIdx.x & 63;
    int net = blockIdx.x * 4 + wv; // NNET == 4 * 50000 exactly
    if (lane < 32) {
        float v = unordf(ymax[(size_t)net * 32 + lane]);
        if (!isfinite(v)) v = 0.f;
        xin[wv][lane] = v;
        if (lane < 16) xin[wv][64 + lane] = xnet[(size_t)net * 16 + lane];
    } else {
        float v = unordf(ymin[(size_t)net * 32 + (lane - 32)]);
        if (!isfinite(v)) v = 0.f;
        xin[wv][lane] = v;
    }
    __syncthreads();
    float acc = b1[lane];
#pragma unroll
    for (int i = 0; i < 80; ++i) acc += xin[wv][i] * w1s[i * 64 + lane];
    float p = tanhf(acc) * w2s[lane];
#pragma unroll
    for (int off = 32; off > 0; off >>= 1) p += __shfl_down(p, off, 64);
    if (lane == 0) out[net] = p + b2[0];
}

extern "C" void kernel_launch(void* const* d_in, const int* in_sizes, int n_in,
                              void* d_out, int out_size, void* d_ws, size_t ws_size,
                              hipStream_t stream) {
    (void)in_sizes; (void)n_in; (void)out_size; (void)ws_size;
    const float* x0   = (const float*)d_in[0];
    const float* xnet = (const float*)d_in[1];
    const float* Ws0 = (const float*)d_in[2];  const float* Wn0 = (const float*)d_in[3];  const float* b0 = (const float*)d_in[4];
    const float* Ws1 = (const float*)d_in[5];  const float* Wn1 = (const float*)d_in[6];  const float* b1 = (const float*)d_in[7];
    const float* Ws2 = (const float*)d_in[8];  const float* Wn2 = (const float*)d_in[9];  const float* b2 = (const float*)d_in[10];
    const float* Ws3 = (const float*)d_in[11]; const float* Wn3 = (const float*)d_in[12]; const float* b3 = (const float*)d_in[13];
    const float* Ws4 = (const float*)d_in[14]; const float* Wn4 = (const float*)d_in[15]; const float* b4 = (const float*)d_in[16];
    const float* mw1 = (const float*)d_in[17]; const float* mb1 = (const float*)d_in[18];
    const float* mw2 = (const float*)d_in[19]; const float* mb2 = (const float*)d_in[20];
    const int* e0s = (const int*)d_in[21]; const int* e0d = (const int*)d_in[22];
    const int* e1s = (const int*)d_in[23]; const int* e1d = (const int*)d_in[24];
    const int* e2s = (const int*)d_in[25]; const int* e2d = (const int*)d_in[26];
    const int* a01 = (const int*)d_in[27]; const int* a12 = (const int*)d_in[28];
    const int* cs  = (const int*)d_in[29]; const int* cd  = (const int*)d_in[30];

    char* ws = (char*)d_ws;
    const size_t MB = 1u << 20;
    // persistent counts (2 MB region at 0)
    float* deg0  = (float*)(ws);                               // N0
    float* deg1  = (float*)(ws + (size_t)N0 * 4);              // N1
    float* deg2  = (float*)(ws + (size_t)(N0 + N1) * 4);       // N2
    float* cnt01 = (float*)(ws + (size_t)(N0 + N1 + N2) * 4);  // N1
    float* cnt12 = (float*)(ws + (size_t)(N0 + 2 * N1 + N2) * 4); // N2
    // aliased big buffers (byte offsets chosen so concurrently-live buffers never overlap)
    float* h0    = (float*)(ws + 2 * MB);     // 32MB, live until cat0 built
    float* h1    = (float*)(ws + 34 * MB);    // 8MB
    float* cat1  = (float*)(ws + 42 * MB);    // 16MB
    float* h1b   = (float*)(ws + 58 * MB);    // 8MB
    float* agg0  = (float*)(ws + 66 * MB);    // 16MB (scratch region)
    float* x1    = (float*)(ws + 66 * MB);    // 8MB  (after agg0 dead)
    float* agg1  = (float*)(ws + 74 * MB);    // 8MB
    float* x2    = (float*)(ws + 82 * MB);    // 2MB
    float* agg2  = (float*)(ws + 84 * MB);    // 2MB
    float* h2    = (float*)(ws + 86 * MB);    // 2MB
    float* aggc1 = (float*)(ws + 66 * MB);    // 16MB (after x1/agg1 dead)
    float* aggc0 = (float*)(ws + 2 * MB);     // 64MB (after h0..h1b dead)
    float* cat0  = (float*)(ws + 130 * MB);   // 64MB
    float* h0b   = (float*)(ws + 66 * MB);    // 64MB (after scratch dead)
    unsigned* ymax = (unsigned*)(ws + 2 * MB);          // 25.6MB (after aggc0 dead)
    unsigned* ymin = ymax + (size_t)NNET * 32;          // contiguous after ymax

    auto g = [](long n, int b) { return dim3((unsigned)((n + b - 1) / b)); };

    // degrees / pool counts
    hipMemsetAsync(ws, 0, 2 * MB, stream);
    deg_kernel<<<g(E0, 256), 256, 0, stream>>>(e0d, E0, deg0);
    deg_kernel<<<g(E1, 256), 256, 0, stream>>>(e1d, E1, deg1);
    deg_kernel<<<g(E2, 256), 256, 0, stream>>>(e2d, E2, deg2);
    deg_kernel<<<g(N0, 256), 256, 0, stream>>>(a01, N0, cnt01);
    deg_kernel<<<g(N1, 256), 256, 0, stream>>>(a12, N1, cnt12);

    // ---- layer 0: h0 = sage(x0, e0)  [N0,32]
    hipMemsetAsync(agg0, 0, (size_t)N0 * 16 * 4, stream);
    scatter_add<16><<<g((long)E0 * 4, 256), 256, 0, stream>>>(x0, e0s, e0d, E0, agg0);
    sage_kernel<16, 32><<<dim3(N0 / 8), 256, 0, stream>>>(x0, agg0, deg0, Ws0, Wn0, b0, h0, N0);

    // ---- pool 0->1: x1 = seg_mean(h0, assign01)  [N1,32]
    hipMemsetAsync(x1, 0, (size_t)N1 * 32 * 4, stream);
    scatter_add<32><<<g((long)N0 * 8, 256), 256, 0, stream>>>(h0, nullptr, a01, N0, x1);
    div_by_count<32><<<g((long)N1 * 32, 256), 256, 0, stream>>>(x1, cnt01, N1);

    // ---- layer 1: h1 = sage(x1, e1)  [N1,32]
    hipMemsetAsync(agg1, 0, (size_t)N1 * 32 * 4, stream);
    scatter_add<32><<<g((long)E1 * 8, 256), 256, 0, stream>>>(x1, e1s, e1d, E1, agg1);
    sage_kernel<32, 32><<<dim3(N1 / 8), 256, 0, stream>>>(x1, agg1, deg1, Ws1, Wn1, b1, h1, N1);

    // ---- pool 1->2: x2 = seg_mean(h1, assign12)  [N2,32]
    hipMemsetAsync(x2, 0, (size_t)N2 * 32 * 4, stream);
    scatter_add<32><<<g((long)N1 * 8, 256), 256, 0, stream>>>(h1, nullptr, a12, N1, x2);
    div_by_count<32><<<g((long)N2 * 32, 256), 256, 0, stream>>>(x2, cnt12, N2);

    // ---- layer 2: h2 = sage(x2, e2)  [N2,32]
    hipMemsetAsync(agg2, 0, (size_t)N2 * 32 * 4, stream);
    scatter_add<32><<<g((long)E2 * 8, 256), 256, 0, stream>>>(x2, e2s, e2d, E2, agg2);
    sage_kernel<32, 32><<<dim3(N2 / 8), 256, 0, stream>>>(x2, agg2, deg2, Ws2, Wn2, b2, h2, N2);

    // ---- up 2->1: cat1 = [h2[assign12], h1]; h1b = sage(cat1, e1)  [N1,32]
    concat_kernel<<<g((long)N1 * 64, 256), 256, 0, stream>>>(h2, a12, h1, cat1, N1);
    hipMemsetAsync(aggc1, 0, (size_t)N1 * 64 * 4, stream);
    scatter_add<64><<<g((long)E1 * 16, 256), 256, 0, stream>>>(cat1, e1s, e1d, E1, aggc1);
    sage_kernel<64, 32><<<dim3(N1 / 8), 256, 0, stream>>>(cat1, aggc1, deg1, Ws3, Wn3, b3, h1b, N1);

    // ---- up 1->0: cat0 = [h1b[assign01], h0]; h0b = sage(cat0, e0)  [N0,64]
    concat_kernel<<<g((long)N0 * 64, 256), 256, 0, stream>>>(h1b, a01, h0, cat0, N0);
    hipMemsetAsync(aggc0, 0, (size_t)N0 * 64 * 4, stream);
    scatter_add<64><<<g((long)E0 * 16, 256), 256, 0, stream>>>(cat0, e0s, e0d, E0, aggc0);
    sage_kernel<64, 64><<<dim3(N0 / 4), 256, 0, stream>>>(cat0, aggc0, deg0, Ws4, Wn4, b4, h0b, N0);

    // ---- per-net segment max of the two 32-wide halves
    init_ord<<<g((long)NNET * 64, 256), 256, 0, stream>>>(ymax, NNET * 64);
    conn_max<<<g((long)ECONN * 32, 256), 256, 0, stream>>>(h0b, cs, cd, ymax, ymin);

    // ---- fused MLP -> out [NNET,1]
    mlp_kernel<<<dim3(NNET / 4), 256, 0, stream>>>(ymax, ymin, xnet, mw1, mb1, mw2, mb2,
                                                   (float*)d_out);
}

// Round 2
// 1638.602 us; speedup vs baseline: 2.5550x; 2.5550x over previous
//
#include <hip/hip_runtime.h>

#define N0 262144
#define N1 65536
#define N2 16384
#define NNET 200000
#define E0 2097152
#define E1 524288
#define E2 131072
#define ECONN 800000

// ================= CSR build =================

__global__ void hist_kernel(const int* __restrict__ idx, int n, int* __restrict__ cnt) {
    int t = blockIdx.x * blockDim.x + threadIdx.x;
    if (t < n) atomicAdd(&cnt[idx[t]], 1);
}

// two-level exclusive scan, 2048 elements per block (256 threads x 8)
__global__ void scan1_kernel(const int* __restrict__ in, int* __restrict__ out,
                             int* __restrict__ partials, int n) {
    __shared__ int ts[256];
    int t = threadIdx.x;
    int base = blockIdx.x * 2048 + t * 8;
    int v[8]; int s = 0;
#pragma unroll
    for (int k = 0; k < 8; ++k) { int i = base + k; v[k] = (i < n) ? in[i] : 0; s += v[k]; }
    ts[t] = s; __syncthreads();
    for (int off = 1; off < 256; off <<= 1) {
        int u = (t >= off) ? ts[t - off] : 0; __syncthreads();
        ts[t] += u; __syncthreads();
    }
    if (t == 255) partials[blockIdx.x] = ts[255];
    int run = ts[t] - s; // exclusive prefix of this thread's chunk
#pragma unroll
    for (int k = 0; k < 8; ++k) { int i = base + k; if (i < n) out[i] = run; run += v[k]; }
}

__global__ void scan2_kernel(int* __restrict__ p, int np) {
    __shared__ int ts[256];
    int t = threadIdx.x;
    int v = (t < np) ? p[t] : 0;
    ts[t] = v; __syncthreads();
    for (int off = 1; off < 256; off <<= 1) {
        int u = (t >= off) ? ts[t - off] : 0; __syncthreads();
        ts[t] += u; __syncthreads();
    }
    if (t < np) p[t] = ts[t] - v; // exclusive
}

__global__ void scan3_kernel(int* __restrict__ out, const int* __restrict__ p, int n) {
    int add = p[blockIdx.x];
    int base = blockIdx.x * 2048;
#pragma unroll
    for (int k = 0; k < 8; ++k) {
        int i = base + k * 256 + threadIdx.x;
        if (i < n) out[i] += add;
    }
}

// scatter edge endpoints into CSR col. src==nullptr -> col = edge index (pooling)
__global__ void scatter_kernel(const int* __restrict__ src, const int* __restrict__ dst,
                               int nE, int* __restrict__ cursor, int* __restrict__ col) {
    int t = blockIdx.x * blockDim.x + threadIdx.x;
    if (t >= nE) return;
    int pos = atomicAdd(&cursor[dst[t]], 1);
    col[pos] = src ? src[t] : t;
}

// ================= fused SAGE: h = tanh(x@Ws + mean_neigh(x)@Wn + b) =================

template<int DIN, int DOUT>
__global__ void sage_csr(const float* __restrict__ x,
                         const int* __restrict__ rp, const int* __restrict__ col,
                         const float* __restrict__ Ws, const float* __restrict__ Wn,
                         const float* __restrict__ bias, float* __restrict__ h, int n) {
    constexpr int G = DOUT;          // threads per node
    constexpr int NPB = 256 / G;     // nodes per block
    __shared__ float ws[DIN * DOUT];
    __shared__ float wn[DIN * DOUT];
    __shared__ float bs[DOUT];
    __shared__ float mean_s[NPB][DIN];
    for (int i = threadIdx.x; i < DIN * DOUT; i += 256) { ws[i] = Ws[i]; wn[i] = Wn[i]; }
    if (threadIdx.x < DOUT) bs[threadIdx.x] = bias[threadIdx.x];
    int g = threadIdx.x / G;
    int tj = threadIdx.x % G;
    int node = blockIdx.x * NPB + g;
    if (node < n) {
        int beg = rp[node], end = rp[node + 1];
        float scale = (end > beg) ? 1.0f / (float)(end - beg) : 0.0f;
        for (int f = tj; f < DIN; f += G) {
            float s = 0.f;
            for (int e = beg; e < end; ++e) s += x[(size_t)col[e] * DIN + f];
            mean_s[g][f] = s * scale;
        }
    }
    __syncthreads();
    if (node < n) {
        const float* xr = &x[(size_t)node * DIN];
        float acc = bs[tj];
#pragma unroll
        for (int i = 0; i < DIN; ++i)
            acc += xr[i] * ws[i * DOUT + tj] + mean_s[g][i] * wn[i * DOUT + tj];
        h[(size_t)node * DOUT + tj] = tanhf(acc);
    }
}

// ================= pooling mean via CSR gather =================

template<int F>
__global__ void csr_mean(const float* __restrict__ x, const int* __restrict__ rp,
                         const int* __restrict__ col, float* __restrict__ out, int n) {
    constexpr int NPB = 256 / F;
    int g = threadIdx.x / F, tj = threadIdx.x % F;
    int seg = blockIdx.x * NPB + g;
    if (seg >= n) return;
    int beg = rp[seg], end = rp[seg + 1];
    float scale = (end > beg) ? 1.0f / (float)(end - beg) : 0.0f;
    float s = 0.f;
    for (int e = beg; e < end; ++e) s += x[(size_t)col[e] * F + tj];
    out[(size_t)seg * F + tj] = s * scale;
}

// ================= cat[n] = [hup[assign[n]] (32) , hlo[n] (32)] =================

__global__ void concat_kernel(const float* __restrict__ hup, const int* __restrict__ assign,
                              const float* __restrict__ hlo, float* __restrict__ cat, int n) {
    int t = blockIdx.x * blockDim.x + threadIdx.x;
    if (t >= n * 64) return;
    int node = t >> 6, f = t & 63;
    float v = (f < 32) ? hup[(size_t)assign[node] * 32 + f]
                       : hlo[(size_t)node * 32 + (f - 32)];
    cat[t] = v;
}

// ================= fused conn-max + MLP: one wave per net =================

__global__ void mlp_kernel(const float* __restrict__ h0b,
                           const int* __restrict__ rp, const int* __restrict__ col,
                           const float* __restrict__ xnet,
                           const float* __restrict__ w1, const float* __restrict__ b1,
                           const float* __restrict__ w2, const float* __restrict__ b2,
                           float* __restrict__ out) {
    __shared__ float w1s[80 * 64];
    __shared__ float w2s[64];
    __shared__ float xin[4][80];
    for (int i = threadIdx.x; i < 80 * 64; i += 256) w1s[i] = w1[i];
    if (threadIdx.x < 64) w2s[threadIdx.x] = w2[threadIdx.x];
    int wv = threadIdx.x >> 6;
    int lane = threadIdx.x & 63;
    int net = blockIdx.x * 4 + wv; // NNET == 4 * 50000 exactly
    int beg = rp[net], end = rp[net + 1];
    float m = -INFINITY;
    for (int e = beg; e < end; ++e)
        m = fmaxf(m, h0b[(size_t)col[e] * 64 + lane]);
    if (beg == end) m = 0.f; // empty net -> 0 (DGL zero init)
    xin[wv][lane] = m;
    if (lane < 16) xin[wv][64 + lane] = xnet[(size_t)net * 16 + lane];
    __syncthreads();
    float acc = b1[lane];
#pragma unroll
    for (int i = 0; i < 80; ++i) acc += xin[wv][i] * w1s[i * 64 + lane];
    float p = tanhf(acc) * w2s[lane];
#pragma unroll
    for (int off = 32; off > 0; off >>= 1) p += __shfl_down(p, off, 64);
    if (lane == 0) out[net] = p + b2[0];
}

// ================= host =================

extern "C" void kernel_launch(void* const* d_in, const int* in_sizes, int n_in,
                              void* d_out, int out_size, void* d_ws, size_t ws_size,
                              hipStream_t stream) {
    (void)in_sizes; (void)n_in; (void)out_size; (void)ws_size;
    const float* x0   = (const float*)d_in[0];
    const float* xnet = (const float*)d_in[1];
    const float* Ws0 = (const float*)d_in[2];  const float* Wn0 = (const float*)d_in[3];  const float* b0 = (const float*)d_in[4];
    const float* Ws1 = (const float*)d_in[5];  const float* Wn1 = (const float*)d_in[6];  const float* b1 = (const float*)d_in[7];
    const float* Ws2 = (const float*)d_in[8];  const float* Wn2 = (const float*)d_in[9];  const float* b2 = (const float*)d_in[10];
    const float* Ws3 = (const float*)d_in[11]; const float* Wn3 = (const float*)d_in[12]; const float* b3 = (const float*)d_in[13];
    const float* Ws4 = (const float*)d_in[14]; const float* Wn4 = (const float*)d_in[15]; const float* b4 = (const float*)d_in[16];
    const float* mw1 = (const float*)d_in[17]; const float* mb1 = (const float*)d_in[18];
    const float* mw2 = (const float*)d_in[19]; const float* mb2 = (const float*)d_in[20];
    const int* e0s = (const int*)d_in[21]; const int* e0d = (const int*)d_in[22];
    const int* e1s = (const int*)d_in[23]; const int* e1d = (const int*)d_in[24];
    const int* e2s = (const int*)d_in[25]; const int* e2d = (const int*)d_in[26];
    const int* a01 = (const int*)d_in[27]; const int* a12 = (const int*)d_in[28];
    const int* cs  = (const int*)d_in[29]; const int* cd  = (const int*)d_in[30];

    char* ws = (char*)d_ws;
    const size_t MB = 1u << 20;
    // ---- int region (CSR) ----
    int* rp0    = (int*)(ws + 0);                       // (N0+1)      @0 .. 1.25MB
    int* col0   = (int*)(ws + (size_t)(1.25 * MB));     // E0 (8MB)
    int* rp1    = (int*)(ws + (size_t)(9.25 * MB));     // (N1+1)
    int* col1   = (int*)(ws + (size_t)(9.5  * MB));     // E1 (2MB)
    int* rp2    = (int*)(ws + (size_t)(11.5 * MB));     // (N2+1)
    int* col2   = (int*)(ws + (size_t)(11.75* MB));     // E2 (0.5MB)
    int* rpA01  = (int*)(ws + (size_t)(12.25* MB));     // (N1+1)
    int* colA01 = (int*)(ws + (size_t)(12.5 * MB));     // N0 (1MB)
    int* rpA12  = (int*)(ws + (size_t)(13.5 * MB));     // (N2+1)
    int* colA12 = (int*)(ws + (size_t)(13.75* MB));     // N1 (0.25MB)
    int* rpC    = (int*)(ws + (size_t)(14.0 * MB));     // (NNET+1) (0.8MB)
    int* colC   = (int*)(ws + (size_t)(14.8 * MB));     // ECONN (3.2MB)
    int* tmp    = (int*)(ws + (size_t)(18.0 * MB));     // counts scratch (N0+1 max)
    int* cursor = (int*)(ws + (size_t)(19.25* MB));     // scatter cursors (N0 max)
    int* partials = (int*)(ws + (size_t)(20.25 * MB));  // <=256 ints
    // ---- float region ----
    float* h0   = (float*)(ws + 21 * MB);   // N0x32 = 32MB  -> 53
    float* h1   = (float*)(ws + 53 * MB);   // N1x32 = 8MB   -> 61
    float* h2   = (float*)(ws + 61 * MB);   // N2x32 = 2MB   -> 63
    float* x1   = (float*)(ws + 63 * MB);   // N1x32 = 8MB   -> 71
    float* x2   = (float*)(ws + 71 * MB);   // N2x32 = 2MB   -> 73
    float* cat1 = (float*)(ws + 73 * MB);   // N1x64 = 16MB  -> 89
    float* h1b  = (float*)(ws + 89 * MB);   // N1x32 = 8MB   -> 97
    float* cat0 = (float*)(ws + 97 * MB);   // N0x64 = 64MB  -> 161
    float* h0b  = (float*)(ws + 21 * MB);   // N0x64 = 64MB, aliases h0..x2 (all dead)

    auto g = [](long n, int b) { return dim3((unsigned)((n + b - 1) / b)); };

    auto build_csr = [&](const int* src, const int* dst, int nE, int nSeg,
                         int* rp, int* colA) {
        hipMemsetAsync(tmp, 0, (size_t)(nSeg + 1) * 4, stream);
        hist_kernel<<<g(nE, 256), 256, 0, stream>>>(dst, nE, tmp);
        int nb = (nSeg + 1 + 2047) / 2048;
        scan1_kernel<<<dim3(nb), 256, 0, stream>>>(tmp, rp, partials, nSeg + 1);
        scan2_kernel<<<dim3(1), 256, 0, stream>>>(partials, nb);
        scan3_kernel<<<dim3(nb), 256, 0, stream>>>(rp, partials, nSeg + 1);
        hipMemcpyAsync(cursor, rp, (size_t)nSeg * 4, hipMemcpyDeviceToDevice, stream);
        scatter_kernel<<<g(nE, 256), 256, 0, stream>>>(src, dst, nE, cursor, colA);
    };

    // ---- build all CSRs (int atomics only, ~5.8M edges total) ----
    build_csr(e0s, e0d, E0, N0, rp0, col0);
    build_csr(e1s, e1d, E1, N1, rp1, col1);
    build_csr(e2s, e2d, E2, N2, rp2, col2);
    build_csr(nullptr, a01, N0, N1, rpA01, colA01);
    build_csr(nullptr, a12, N1, N2, rpA12, colA12);
    build_csr(cs, cd, ECONN, NNET, rpC, colC);

    // ---- layer 0: h0 = sage(x0, e0)  [N0,32]
    sage_csr<16, 32><<<dim3(N0 / 8), 256, 0, stream>>>(x0, rp0, col0, Ws0, Wn0, b0, h0, N0);
    // ---- pool 0->1: x1 = seg_mean(h0, assign01)  [N1,32]
    csr_mean<32><<<dim3(N1 / 8), 256, 0, stream>>>(h0, rpA01, colA01, x1, N1);
    // ---- layer 1: h1 = sage(x1, e1)  [N1,32]
    sage_csr<32, 32><<<dim3(N1 / 8), 256, 0, stream>>>(x1, rp1, col1, Ws1, Wn1, b1, h1, N1);
    // ---- pool 1->2: x2 = seg_mean(h1, assign12)  [N2,32]
    csr_mean<32><<<dim3(N2 / 8), 256, 0, stream>>>(h1, rpA12, colA12, x2, N2);
    // ---- layer 2: h2 = sage(x2, e2)  [N2,32]
    sage_csr<32, 32><<<dim3(N2 / 8), 256, 0, stream>>>(x2, rp2, col2, Ws2, Wn2, b2, h2, N2);
    // ---- up 2->1: cat1 = [h2[assign12], h1]; h1b = sage(cat1, e1)  [N1,32]
    concat_kernel<<<g((long)N1 * 64, 256), 256, 0, stream>>>(h2, a12, h1, cat1, N1);
    sage_csr<64, 32><<<dim3(N1 / 8), 256, 0, stream>>>(cat1, rp1, col1, Ws3, Wn3, b3, h1b, N1);
    // ---- up 1->0: cat0 = [h1b[assign01], h0]; h0b = sage(cat0, e0)  [N0,64]
    concat_kernel<<<g((long)N0 * 64, 256), 256, 0, stream>>>(h1b, a01, h0, cat0, N0);
    sage_csr<64, 64><<<dim3(N0 / 4), 256, 0, stream>>>(cat0, rp0, col0, Ws4, Wn4, b4, h0b, N0);
    // ---- fused per-net segment-max + MLP -> out [NNET,1]
    mlp_kernel<<<dim3(NNET / 4), 256, 0, stream>>>(h0b, rpC, colC, xnet, mw1, mb1, mw2, mb2,
                                                   (float*)d_out);
}

// Round 3
// 1112.068 us; speedup vs baseline: 3.7647x; 1.4735x over previous
//
#include <hip/hip_runtime.h>

#define N0 262144
#define N1 65536
#define N2 16384
#define NNET 200000
#define E0 2097152
#define E1 524288
#define E2 131072
#define ECONN 800000

// ================= CSR build =================

__global__ void hist_kernel(const int* __restrict__ idx, int n, int* __restrict__ cnt) {
    int t = blockIdx.x * blockDim.x + threadIdx.x;
    if (t < n) atomicAdd(&cnt[idx[t]], 1);
}

// two-level exclusive scan, 2048 elements per block (256 threads x 8)
__global__ void scan1_kernel(const int* __restrict__ in, int* __restrict__ out,
                             int* __restrict__ partials, int n) {
    __shared__ int ts[256];
    int t = threadIdx.x;
    int base = blockIdx.x * 2048 + t * 8;
    int v[8]; int s = 0;
#pragma unroll
    for (int k = 0; k < 8; ++k) { int i = base + k; v[k] = (i < n) ? in[i] : 0; s += v[k]; }
    ts[t] = s; __syncthreads();
    for (int off = 1; off < 256; off <<= 1) {
        int u = (t >= off) ? ts[t - off] : 0; __syncthreads();
        ts[t] += u; __syncthreads();
    }
    if (t == 255) partials[blockIdx.x] = ts[255];
    int run = ts[t] - s; // exclusive prefix of this thread's chunk
#pragma unroll
    for (int k = 0; k < 8; ++k) { int i = base + k; if (i < n) out[i] = run; run += v[k]; }
}

__global__ void scan2_kernel(int* __restrict__ p, int np) {
    __shared__ int ts[256];
    int t = threadIdx.x;
    int v = (t < np) ? p[t] : 0;
    ts[t] = v; __syncthreads();
    for (int off = 1; off < 256; off <<= 1) {
        int u = (t >= off) ? ts[t - off] : 0; __syncthreads();
        ts[t] += u; __syncthreads();
    }
    if (t < np) p[t] = ts[t] - v; // exclusive
}

__global__ void scan3_kernel(int* __restrict__ out, const int* __restrict__ p, int n) {
    int add = p[blockIdx.x];
    int base = blockIdx.x * 2048;
#pragma unroll
    for (int k = 0; k < 8; ++k) {
        int i = base + k * 256 + threadIdx.x;
        if (i < n) out[i] += add;
    }
}

// scatter edge endpoints into CSR col. src==nullptr -> col = edge index (pooling)
__global__ void scatter_kernel(const int* __restrict__ src, const int* __restrict__ dst,
                               int nE, int* __restrict__ cursor, int* __restrict__ col) {
    int t = blockIdx.x * blockDim.x + threadIdx.x;
    if (t >= nE) return;
    int pos = atomicAdd(&cursor[dst[t]], 1);
    col[pos] = src ? src[t] : t;
}

// ================= fused SAGE: h = tanh(x@Ws + mean_neigh(x)@Wn + b) =================
// G = DOUT lanes per node; EP = G/(DIN/4) edges gathered in parallel (float4/lane);
// transposed + padded weights in LDS so phase B streams ds_read_b128 conflict-free.

template<int DIN, int DOUT, int BLK>
__global__ __launch_bounds__(BLK) void sage_csr(const float* __restrict__ x,
                         const int* __restrict__ rp, const int* __restrict__ col,
                         const float* __restrict__ Ws, const float* __restrict__ Wn,
                         const float* __restrict__ bias, float* __restrict__ h, int n) {
    constexpr int G   = DOUT;       // threads per node
    constexpr int NPB = BLK / G;    // nodes per block
    constexpr int L4  = DIN / 4;    // lanes covering one row as float4
    constexpr int EP  = G / L4;     // edges in flight per node
    constexpr int SD  = DIN + 4;    // padded LDS stride (banks 4j%32 -> conflict-free b128)
    __shared__ float wsT[DOUT * SD];
    __shared__ float wnT[DOUT * SD];
    __shared__ float bs[DOUT];
    __shared__ float xs[NPB][SD];
    __shared__ float ms[NPB][SD];
    for (int idx = threadIdx.x; idx < DIN * DOUT; idx += BLK) {
        int i = idx / DOUT, j = idx % DOUT;
        wsT[j * SD + i] = Ws[idx];
        wnT[j * SD + i] = Wn[idx];
    }
    if (threadIdx.x < DOUT) bs[threadIdx.x] = bias[threadIdx.x];
    const int g = threadIdx.x / G;
    const int tg = threadIdx.x % G;
    const int rowlane = tg % L4;
    const int esub = tg / L4;
    const int node = blockIdx.x * NPB + g;
    float4 s = make_float4(0.f, 0.f, 0.f, 0.f);
    float4 own = make_float4(0.f, 0.f, 0.f, 0.f);
    int beg = 0, end = 0;
    if (node < n) {
        beg = rp[node]; end = rp[node + 1];
        if (esub == 0)
            own = *reinterpret_cast<const float4*>(&x[(size_t)node * DIN + rowlane * 4]);
#pragma unroll 2
        for (int e0 = beg; e0 < end; e0 += EP) {
            int e = e0 + esub;
            if (e < end) {
                int c = col[e];
                const float4 v = *reinterpret_cast<const float4*>(&x[(size_t)c * DIN + rowlane * 4]);
                s.x += v.x; s.y += v.y; s.z += v.z; s.w += v.w;
            }
        }
    }
#pragma unroll
    for (int m = L4; m < G; m <<= 1) {
        s.x += __shfl_xor(s.x, m, 64);
        s.y += __shfl_xor(s.y, m, 64);
        s.z += __shfl_xor(s.z, m, 64);
        s.w += __shfl_xor(s.w, m, 64);
    }
    if (node < n && esub == 0) {
        float sc = (end > beg) ? 1.0f / (float)(end - beg) : 0.f;
        *reinterpret_cast<float4*>(&ms[g][rowlane * 4]) =
            make_float4(s.x * sc, s.y * sc, s.z * sc, s.w * sc);
        *reinterpret_cast<float4*>(&xs[g][rowlane * 4]) = own;
    }
    __syncthreads();
    if (node >= n) return;
    const int j = tg;
    float acc = bs[j];
#pragma unroll
    for (int i = 0; i < DIN; i += 4) {
        const float4 w4 = *reinterpret_cast<const float4*>(&wsT[j * SD + i]);
        const float4 n4 = *reinterpret_cast<const float4*>(&wnT[j * SD + i]);
        const float4 xv = *reinterpret_cast<const float4*>(&xs[g][i]);
        const float4 mv = *reinterpret_cast<const float4*>(&ms[g][i]);
        acc += xv.x * w4.x + xv.y * w4.y + xv.z * w4.z + xv.w * w4.w
             + mv.x * n4.x + mv.y * n4.y + mv.z * n4.z + mv.w * n4.w;
    }
    h[(size_t)node * DOUT + j] = tanhf(acc);
}

// ================= pooling mean via CSR gather (F=32, 32 lanes/segment) =================

template<int F>
__global__ void csr_mean(const float* __restrict__ x, const int* __restrict__ rp,
                         const int* __restrict__ col, float* __restrict__ out, int n) {
    constexpr int G = 32, L4 = F / 4, EP = G / L4;
    int g = threadIdx.x / G, tg = threadIdx.x % G;
    int rowlane = tg % L4, esub = tg / L4;
    int seg = blockIdx.x * (256 / G) + g;
    if (seg >= n) return;
    int beg = rp[seg], end = rp[seg + 1];
    float4 s = make_float4(0.f, 0.f, 0.f, 0.f);
    for (int e0 = beg; e0 < end; e0 += EP) {
        int e = e0 + esub;
        if (e < end) {
            int c = col[e];
            const float4 v = *reinterpret_cast<const float4*>(&x[(size_t)c * F + rowlane * 4]);
            s.x += v.x; s.y += v.y; s.z += v.z; s.w += v.w;
        }
    }
#pragma unroll
    for (int m = L4; m < G; m <<= 1) {
        s.x += __shfl_xor(s.x, m, 64);
        s.y += __shfl_xor(s.y, m, 64);
        s.z += __shfl_xor(s.z, m, 64);
        s.w += __shfl_xor(s.w, m, 64);
    }
    if (esub == 0) {
        float sc = (end > beg) ? 1.0f / (float)(end - beg) : 0.f;
        *reinterpret_cast<float4*>(&out[(size_t)seg * F + rowlane * 4]) =
            make_float4(s.x * sc, s.y * sc, s.z * sc, s.w * sc);
    }
}

// ================= cat[n] = [hup[assign[n]] (32) , hlo[n] (32)], float4 =================

__global__ void concat_kernel(const float* __restrict__ hup, const int* __restrict__ assign,
                              const float* __restrict__ hlo, float* __restrict__ cat, int n) {
    int t = blockIdx.x * blockDim.x + threadIdx.x; // over n*16 float4s
    if (t >= n * 16) return;
    int node = t >> 4, c = t & 15;
    float4 v;
    if (c < 8) v = *reinterpret_cast<const float4*>(&hup[(size_t)assign[node] * 32 + c * 4]);
    else       v = *reinterpret_cast<const float4*>(&hlo[(size_t)node * 32 + (c - 8) * 4]);
    *reinterpret_cast<float4*>(&cat[(size_t)t * 4]) = v;
}

// ================= fused conn-max + MLP: one wave per net, float4 gathers =================

__global__ __launch_bounds__(512) void mlp_kernel(const float* __restrict__ h0b,
                           const int* __restrict__ rp, const int* __restrict__ col,
                           const float* __restrict__ xnet,
                           const float* __restrict__ w1, const float* __restrict__ b1,
                           const float* __restrict__ w2, const float* __restrict__ b2,
                           float* __restrict__ out) {
    constexpr int SD = 84;
    __shared__ float w1T[64 * SD];
    __shared__ float w2s[64];
    __shared__ float xin[8][SD];
    for (int idx = threadIdx.x; idx < 80 * 64; idx += 512) {
        int i = idx / 64, j = idx % 64;
        w1T[j * SD + i] = w1[idx];
    }
    if (threadIdx.x < 64) w2s[threadIdx.x] = w2[threadIdx.x];
    int wv = threadIdx.x >> 6;
    int lane = threadIdx.x & 63;
    int rowlane = lane & 15, esub = lane >> 4;
    int net = blockIdx.x * 8 + wv; // NNET == 8 * 25000
    int beg = rp[net], end = rp[net + 1];
    float4 m = make_float4(-INFINITY, -INFINITY, -INFINITY, -INFINITY);
    for (int e0 = beg; e0 < end; e0 += 4) {
        int e = e0 + esub;
        if (e < end) {
            int c = col[e];
            const float4 v = *reinterpret_cast<const float4*>(&h0b[(size_t)c * 64 + rowlane * 4]);
            m.x = fmaxf(m.x, v.x); m.y = fmaxf(m.y, v.y);
            m.z = fmaxf(m.z, v.z); m.w = fmaxf(m.w, v.w);
        }
    }
#pragma unroll
    for (int msk = 16; msk < 64; msk <<= 1) {
        m.x = fmaxf(m.x, __shfl_xor(m.x, msk, 64));
        m.y = fmaxf(m.y, __shfl_xor(m.y, msk, 64));
        m.z = fmaxf(m.z, __shfl_xor(m.z, msk, 64));
        m.w = fmaxf(m.w, __shfl_xor(m.w, msk, 64));
    }
    if (beg == end) m = make_float4(0.f, 0.f, 0.f, 0.f); // empty net -> 0
    if (esub == 0) *reinterpret_cast<float4*>(&xin[wv][rowlane * 4]) = m;
    else if (esub == 1) xin[wv][64 + rowlane] = xnet[(size_t)net * 16 + rowlane];
    __syncthreads();
    float acc = b1[lane];
#pragma unroll
    for (int i = 0; i < 80; i += 4) {
        const float4 w4 = *reinterpret_cast<const float4*>(&w1T[lane * SD + i]);
        const float4 xv = *reinterpret_cast<const float4*>(&xin[wv][i]);
        acc += xv.x * w4.x + xv.y * w4.y + xv.z * w4.z + xv.w * w4.w;
    }
    float p = tanhf(acc) * w2s[lane];
#pragma unroll
    for (int off = 32; off > 0; off >>= 1) p += __shfl_down(p, off, 64);
    if (lane == 0) out[net] = p + b2[0];
}

// ================= host =================

extern "C" void kernel_launch(void* const* d_in, const int* in_sizes, int n_in,
                              void* d_out, int out_size, void* d_ws, size_t ws_size,
                              hipStream_t stream) {
    (void)in_sizes; (void)n_in; (void)out_size; (void)ws_size;
    const float* x0   = (const float*)d_in[0];
    const float* xnet = (const float*)d_in[1];
    const float* Ws0 = (const float*)d_in[2];  const float* Wn0 = (const float*)d_in[3];  const float* b0 = (const float*)d_in[4];
    const float* Ws1 = (const float*)d_in[5];  const float* Wn1 = (const float*)d_in[6];  const float* b1 = (const float*)d_in[7];
    const float* Ws2 = (const float*)d_in[8];  const float* Wn2 = (const float*)d_in[9];  const float* b2 = (const float*)d_in[10];
    const float* Ws3 = (const float*)d_in[11]; const float* Wn3 = (const float*)d_in[12]; const float* b3 = (const float*)d_in[13];
    const float* Ws4 = (const float*)d_in[14]; const float* Wn4 = (const float*)d_in[15]; const float* b4 = (const float*)d_in[16];
    const float* mw1 = (const float*)d_in[17]; const float* mb1 = (const float*)d_in[18];
    const float* mw2 = (const float*)d_in[19]; const float* mb2 = (const float*)d_in[20];
    const int* e0s = (const int*)d_in[21]; const int* e0d = (const int*)d_in[22];
    const int* e1s = (const int*)d_in[23]; const int* e1d = (const int*)d_in[24];
    const int* e2s = (const int*)d_in[25]; const int* e2d = (const int*)d_in[26];
    const int* a01 = (const int*)d_in[27]; const int* a12 = (const int*)d_in[28];
    const int* cs  = (const int*)d_in[29]; const int* cd  = (const int*)d_in[30];

    char* ws = (char*)d_ws;
    const size_t MB = 1u << 20;
    // ---- int region (CSR) ----
    int* rp0    = (int*)(ws + 0);                       // (N0+1)
    int* col0   = (int*)(ws + (size_t)(1.25 * MB));     // E0 (8MB)
    int* rp1    = (int*)(ws + (size_t)(9.25 * MB));     // (N1+1)
    int* col1   = (int*)(ws + (size_t)(9.5  * MB));     // E1 (2MB)
    int* rp2    = (int*)(ws + (size_t)(11.5 * MB));     // (N2+1)
    int* col2   = (int*)(ws + (size_t)(11.75* MB));     // E2 (0.5MB)
    int* rpA01  = (int*)(ws + (size_t)(12.25* MB));     // (N1+1)
    int* colA01 = (int*)(ws + (size_t)(12.5 * MB));     // N0 (1MB)
    int* rpA12  = (int*)(ws + (size_t)(13.5 * MB));     // (N2+1)
    int* colA12 = (int*)(ws + (size_t)(13.75* MB));     // N1 (0.25MB)
    int* rpC    = (int*)(ws + (size_t)(14.0 * MB));     // (NNET+1)
    int* colC   = (int*)(ws + (size_t)(14.8 * MB));     // ECONN (3.2MB)
    int* tmp    = (int*)(ws + (size_t)(18.0 * MB));     // counts scratch
    int* cursor = (int*)(ws + (size_t)(19.25* MB));     // scatter cursors
    int* partials = (int*)(ws + (size_t)(20.25 * MB));  // <=256 ints
    // ---- float region ----
    float* h0   = (float*)(ws + 21 * MB);   // N0x32 = 32MB
    float* h1   = (float*)(ws + 53 * MB);   // N1x32 = 8MB
    float* h2   = (float*)(ws + 61 * MB);   // N2x32 = 2MB
    float* x1   = (float*)(ws + 63 * MB);   // N1x32 = 8MB
    float* x2   = (float*)(ws + 71 * MB);   // N2x32 = 2MB
    float* cat1 = (float*)(ws + 73 * MB);   // N1x64 = 16MB
    float* h1b  = (float*)(ws + 89 * MB);   // N1x32 = 8MB
    float* cat0 = (float*)(ws + 97 * MB);   // N0x64 = 64MB
    float* h0b  = (float*)(ws + 21 * MB);   // N0x64 = 64MB, aliases h0..x2 (dead)

    auto g = [](long n, int b) { return dim3((unsigned)((n + b - 1) / b)); };

    auto build_csr = [&](const int* src, const int* dst, int nE, int nSeg,
                         int* rp, int* colA) {
        hipMemsetAsync(tmp, 0, (size_t)(nSeg + 1) * 4, stream);
        hist_kernel<<<g(nE, 256), 256, 0, stream>>>(dst, nE, tmp);
        int nb = (nSeg + 1 + 2047) / 2048;
        scan1_kernel<<<dim3(nb), 256, 0, stream>>>(tmp, rp, partials, nSeg + 1);
        scan2_kernel<<<dim3(1), 256, 0, stream>>>(partials, nb);
        scan3_kernel<<<dim3(nb), 256, 0, stream>>>(rp, partials, nSeg + 1);
        hipMemcpyAsync(cursor, rp, (size_t)nSeg * 4, hipMemcpyDeviceToDevice, stream);
        scatter_kernel<<<g(nE, 256), 256, 0, stream>>>(src, dst, nE, cursor, colA);
    };

    // ---- build all CSRs (int atomics only) ----
    build_csr(e0s, e0d, E0, N0, rp0, col0);
    build_csr(e1s, e1d, E1, N1, rp1, col1);
    build_csr(e2s, e2d, E2, N2, rp2, col2);
    build_csr(nullptr, a01, N0, N1, rpA01, colA01);
    build_csr(nullptr, a12, N1, N2, rpA12, colA12);
    build_csr(cs, cd, ECONN, NNET, rpC, colC);

    // ---- layer 0: h0 = sage(x0, e0)  [N0,32]
    sage_csr<16, 32, 256><<<dim3(N0 / 8), 256, 0, stream>>>(x0, rp0, col0, Ws0, Wn0, b0, h0, N0);
    // ---- pool 0->1: x1 = seg_mean(h0, assign01)  [N1,32]
    csr_mean<32><<<dim3(N1 / 8), 256, 0, stream>>>(h0, rpA01, colA01, x1, N1);
    // ---- layer 1: h1 = sage(x1, e1)  [N1,32]
    sage_csr<32, 32, 256><<<dim3(N1 / 8), 256, 0, stream>>>(x1, rp1, col1, Ws1, Wn1, b1, h1, N1);
    // ---- pool 1->2: x2 = seg_mean(h1, assign12)  [N2,32]
    csr_mean<32><<<dim3(N2 / 8), 256, 0, stream>>>(h1, rpA12, colA12, x2, N2);
    // ---- layer 2: h2 = sage(x2, e2)  [N2,32]
    sage_csr<32, 32, 256><<<dim3(N2 / 8), 256, 0, stream>>>(x2, rp2, col2, Ws2, Wn2, b2, h2, N2);
    // ---- up 2->1: cat1 = [h2[assign12], h1]; h1b = sage(cat1, e1)  [N1,32]
    concat_kernel<<<g((long)N1 * 16, 256), 256, 0, stream>>>(h2, a12, h1, cat1, N1);
    sage_csr<64, 32, 512><<<dim3(N1 / 16), 512, 0, stream>>>(cat1, rp1, col1, Ws3, Wn3, b3, h1b, N1);
    // ---- up 1->0: cat0 = [h1b[assign01], h0]; h0b = sage(cat0, e0)  [N0,64]
    concat_kernel<<<g((long)N0 * 16, 256), 256, 0, stream>>>(h1b, a01, h0, cat0, N0);
    sage_csr<64, 64, 512><<<dim3(N0 / 8), 512, 0, stream>>>(cat0, rp0, col0, Ws4, Wn4, b4, h0b, N0);
    // ---- fused per-net segment-max + MLP -> out [NNET,1]
    mlp_kernel<<<dim3(NNET / 8), 512, 0, stream>>>(h0b, rpC, colC, xnet, mw1, mb1, mw2, mb2,
                                                   (float*)d_out);
}